// Round 3
// baseline (133.803 us; speedup 1.0000x reference)
//
#include <hip/hip_runtime.h>
#include <hip/hip_bf16.h>

#define BT    8192      // B*T tokens (4*2048)
#define SEQ_T 2048
#define DIN   1024
#define NH    16
#define NK    8
#define DH    64
#define DO    64

typedef __bf16 bf16;
typedef __attribute__((ext_vector_type(8))) __bf16 bf16x8;
typedef __attribute__((ext_vector_type(4))) __bf16 bf16x4;
typedef __attribute__((ext_vector_type(4))) float floatx4;

// ---------------------------------------------------------------------------
// Kernel 1: (a) scores_t[k][token] = phi[t,k] + x[token,:]·diag[k,:]  (fp32)
//           2 tokens per wave so each diag float4 is reused twice (halves the
//           L1 diag traffic vs 1 token/wave).
//           (b) wt[h][k][o][i] = bf16(W[h][k][i][o]) via LDS transpose.
// ---------------------------------------------------------------------------
__global__ __launch_bounds__(256) void prep_kernel(
    const float* __restrict__ x, const float* __restrict__ weight,
    const float* __restrict__ diag, const float* __restrict__ phi,
    float* __restrict__ scores_t, bf16* __restrict__ wt)
{
  int blk = blockIdx.x, tid = threadIdx.x;
  if (blk < BT / 8) {
    // ---- scores: 4 waves/block, 2 tokens/wave ----
    int wave = tid >> 6, lane = tid & 63;
    int tok = blk * 8 + wave * 2;
    const floatx4* xr0 = (const floatx4*)(x + (size_t)tok * DIN);
    const floatx4* xr1 = (const floatx4*)(x + (size_t)(tok + 1) * DIN);
    const floatx4* dg  = (const floatx4*)diag;
    floatx4 a0[NK], a1[NK];
#pragma unroll
    for (int k = 0; k < NK; k++) {
      a0[k] = (floatx4){0.f, 0.f, 0.f, 0.f};
      a1[k] = (floatx4){0.f, 0.f, 0.f, 0.f};
    }
#pragma unroll
    for (int it = 0; it < 4; it++) {
      floatx4 xv0 = xr0[it * 64 + lane];
      floatx4 xv1 = xr1[it * 64 + lane];
#pragma unroll
      for (int k = 0; k < NK; k++) {
        floatx4 dv = dg[k * 256 + it * 64 + lane];
        a0[k] += xv0 * dv;
        a1[k] += xv1 * dv;
      }
    }
    float r0[NK], r1[NK];
#pragma unroll
    for (int k = 0; k < NK; k++) {
      r0[k] = (a0[k][0] + a0[k][1]) + (a0[k][2] + a0[k][3]);
      r1[k] = (a1[k][0] + a1[k][1]) + (a1[k][2] + a1[k][3]);
    }
#pragma unroll
    for (int k = 0; k < NK; k++) {
      float v0 = r0[k], v1 = r1[k];
#pragma unroll
      for (int off = 32; off >= 1; off >>= 1) {
        v0 += __shfl_xor(v0, off, 64);
        v1 += __shfl_xor(v1, off, 64);
      }
      r0[k] = v0; r1[k] = v1;
    }
    if (lane == 0) {
      int t = tok & (SEQ_T - 1);
#pragma unroll
      for (int k = 0; k < NK; k++) {
        scores_t[(size_t)k * BT + tok]     = phi[t * NK + k]       + r0[k];
        scores_t[(size_t)k * BT + tok + 1] = phi[(t + 1) * NK + k] + r1[k];
      }
    }
  } else {
    // ---- weight transpose: one (h,k) 64x64 tile per block, coalesced both sides ----
    __shared__ bf16 tile[64 * 68];
    int hk = blk - BT / 8;
    const float* wsrc = weight + (size_t)hk * DH * DO;
#pragma unroll
    for (int it = 0; it < 4; it++) {
      int idx = it * 1024 + tid * 4;
      int i = idx >> 6, o = idx & 63;
      floatx4 v = *(const floatx4*)(wsrc + idx);
#pragma unroll
      for (int r = 0; r < 4; r++)
        tile[(o + r) * 68 + i] = (bf16)v[r];
    }
    __syncthreads();
#pragma unroll
    for (int it = 0; it < 4; it++) {
      int idx = it * 1024 + tid * 4;
      int o2 = idx >> 6, i2 = idx & 63;
      bf16x4 v = *(const bf16x4*)&tile[o2 * 68 + i2];
      *(bf16x4*)(wt + (size_t)hk * 4096 + idx) = v;
    }
  }
}

// ---------------------------------------------------------------------------
// Kernel 2 (v3): NO LDS, NO barriers. Block = (token group of 128, head h),
// 4 waves; wave owns a 16-col output slice and holds ALL 8 experts' B
// fragments persistently in registers (64 VGPRs). Loops over 4 token-tiles
// of 32 rows with double-buffered global A loads (x rows are 128B-line
// aligned & fully coalesced). Scores read directly from L1/L2 (broadcast).
// Per tile per wave: 16 MFMAs + 16 scale-FMA4s + 8 stores.
// ---------------------------------------------------------------------------
__global__ __launch_bounds__(256) void moe_kernel(
    const float* __restrict__ x, const bf16* __restrict__ wt,
    const float* __restrict__ scores_t, float* __restrict__ out)
{
  int g = blockIdx.x >> 4;            // token group 0..63 (128 tokens each)
  int h = blockIdx.x & (NH - 1);      // concurrent blocks span all heads
  int tid = threadIdx.x, lane = tid & 63, w = tid >> 6;
  int l15 = lane & 15, q = lane >> 4;
  int C0 = w * 16;                    // wave's 16-col slice
  int tg0 = g * 128;

  // ---- persistent B fragments: B[i=ki*32+q*8+j][o=C0+l15] from wt[h][k][o][i]
  bf16x8 b[NK][2];
  {
    const bf16* wh = wt + (size_t)h * NK * DO * DH;
#pragma unroll
    for (int k = 0; k < NK; k++) {
      const bf16* bp = wh + ((size_t)k * DO + C0 + l15) * DH + q * 8;
      b[k][0] = *(const bf16x8*)bp;
      b[k][1] = *(const bf16x8*)(bp + 32);
    }
  }

  const float* xc = x + (size_t)h * DH;
  floatx4 af[2][2][2][2];             // [buf][rb][ki][half]

  // ---- load tile 0's A (rows tg0 .. tg0+31) ----
#pragma unroll
  for (int rb = 0; rb < 2; rb++) {
    const float* rp = xc + (size_t)(tg0 + rb * 16 + l15) * DIN;
#pragma unroll
    for (int ki = 0; ki < 2; ki++) {
      const floatx4* p = (const floatx4*)(rp + ki * 32 + q * 8);
      af[0][rb][ki][0] = p[0];
      af[0][rb][ki][1] = p[1];
    }
  }

#pragma unroll
  for (int t = 0; t < 4; t++) {
    int tr = tg0 + t * 32;
    // prefetch next tile's A into the other buffer (skip on last tile)
    if (t < 3) {
#pragma unroll
      for (int rb = 0; rb < 2; rb++) {
        const float* rp = xc + (size_t)(tr + 32 + rb * 16 + l15) * DIN;
#pragma unroll
        for (int ki = 0; ki < 2; ki++) {
          const floatx4* p = (const floatx4*)(rp + ki * 32 + q * 8);
          af[(t + 1) & 1][rb][ki][0] = p[0];
          af[(t + 1) & 1][rb][ki][1] = p[1];
        }
      }
    }
    // convert current tile's A to bf16 fragments
    bf16x8 a[2][2];
#pragma unroll
    for (int rb = 0; rb < 2; rb++)
#pragma unroll
      for (int ki = 0; ki < 2; ki++) {
        floatx4 f0 = af[t & 1][rb][ki][0], f1 = af[t & 1][rb][ki][1];
        bf16x8 av;
        av[0] = (bf16)f0[0]; av[1] = (bf16)f0[1];
        av[2] = (bf16)f0[2]; av[3] = (bf16)f0[3];
        av[4] = (bf16)f1[0]; av[5] = (bf16)f1[1];
        av[6] = (bf16)f1[2]; av[7] = (bf16)f1[3];
        a[rb][ki] = av;
      }

    floatx4 y0 = (floatx4){0.f, 0.f, 0.f, 0.f};
    floatx4 y1 = (floatx4){0.f, 0.f, 0.f, 0.f};
#pragma unroll
    for (int k = 0; k < NK; k++) {
      floatx4 s0 = *(const floatx4*)(scores_t + (size_t)k * BT + tr + q * 4);
      floatx4 s1 = *(const floatx4*)(scores_t + (size_t)k * BT + tr + 16 + q * 4);
      floatx4 z0 = (floatx4){0.f, 0.f, 0.f, 0.f};
      z0 = __builtin_amdgcn_mfma_f32_16x16x32_bf16(a[0][0], b[k][0], z0, 0, 0, 0);
      z0 = __builtin_amdgcn_mfma_f32_16x16x32_bf16(a[0][1], b[k][1], z0, 0, 0, 0);
      y0 += s0 * z0;
      floatx4 z1 = (floatx4){0.f, 0.f, 0.f, 0.f};
      z1 = __builtin_amdgcn_mfma_f32_16x16x32_bf16(a[1][0], b[k][0], z1, 0, 0, 0);
      z1 = __builtin_amdgcn_mfma_f32_16x16x32_bf16(a[1][1], b[k][1], z1, 0, 0, 0);
      y1 += s1 * z1;
    }
    // store: C/D layout col=l15, row=q*4+r
#pragma unroll
    for (int r = 0; r < 4; r++) {
      out[(size_t)(tr + q * 4 + r) * (NH * DO) + h * DO + C0 + l15]      = y0[r];
      out[(size_t)(tr + 16 + q * 4 + r) * (NH * DO) + h * DO + C0 + l15] = y1[r];
    }
  }
}

extern "C" void kernel_launch(void* const* d_in, const int* in_sizes, int n_in,
                              void* d_out, int out_size, void* d_ws, size_t ws_size,
                              hipStream_t stream) {
  const float* x      = (const float*)d_in[0];
  const float* weight = (const float*)d_in[1];
  const float* diag   = (const float*)d_in[2];
  const float* phi    = (const float*)d_in[3];
  float* out = (float*)d_out;

  // workspace: [0, 1MiB) bf16 transposed weights; then scores_t (256 KiB)
  bf16*  wt       = (bf16*)d_ws;
  float* scores_t = (float*)((char*)d_ws + (size_t)NH * NK * DH * DO * 2);

  prep_kernel<<<BT / 8 + NH * NK, 256, 0, stream>>>(x, weight, diag, phi, scores_t, wt);
  moe_kernel<<<64 * NH, 256, 0, stream>>>(x, wt, scores_t, out);
}